// Round 3
// baseline (83.827 us; speedup 1.0000x reference)
//
#include <hip/hip_runtime.h>

#define NNODES 1024
#define NHEADS 8
#define NHID 16
#define DIM 128            // NHEADS * NHID
#define NEG_SLOPE 0.2f

// quad broadcast via DPP quad_perm
template<int CTRL>
__device__ __forceinline__ float qbcast(float v) {
    return __int_as_float(__builtin_amdgcn_mov_dpp(__float_as_int(v), CTRL, 0xF, 0xF, true));
}

// K1: g = h @ W^T tiled 16(i) x 16(one head); src/dst reductions fused.
// 4 independent FMA chains (was 1 x 128-deep: exposed ~512cy latency at 2 waves/SIMD).
__global__ __launch_bounds__(256) void proj_kernel(
    const float* __restrict__ h, const float* __restrict__ W,
    const float* __restrict__ attn_w,
    float* __restrict__ g, float* __restrict__ srcv, float* __restrict__ dstv)
{
    const int bi = blockIdx.x & 63;   // i-tile
    const int bh = blockIdx.x >> 6;   // head
    const int i0 = bi << 4;
    const int tid = threadIdx.x;
    __shared__ float4 hs[16][33];
    __shared__ float4 ws[16][33];
    const float4* h4 = (const float4*)h;   // 32 float4 per row
    const float4* W4 = (const float4*)W;
    {
        const int t0 = tid, t1 = tid + 256;
        hs[t0 >> 5][t0 & 31] = h4[(size_t)i0 * 32 + t0];
        hs[t1 >> 5][t1 & 31] = h4[(size_t)i0 * 32 + t1];
        ws[t0 >> 5][t0 & 31] = W4[(size_t)(bh * 16) * 32 + t0];
        ws[t1 >> 5][t1 & 31] = W4[(size_t)(bh * 16) * 32 + t1];
    }
    __syncthreads();
    const int il = tid >> 4;          // 0..15 local row
    const int f  = tid & 15;          // 0..15 feature within head
    float p0 = 0.f, p1 = 0.f, p2 = 0.f, p3 = 0.f;
#pragma unroll
    for (int k = 0; k < 32; k += 4) {
        float4 a, b;
        a = hs[il][k];     b = ws[f][k];
        p0 = fmaf(a.x, b.x, fmaf(a.y, b.y, fmaf(a.z, b.z, fmaf(a.w, b.w, p0))));
        a = hs[il][k + 1]; b = ws[f][k + 1];
        p1 = fmaf(a.x, b.x, fmaf(a.y, b.y, fmaf(a.z, b.z, fmaf(a.w, b.w, p1))));
        a = hs[il][k + 2]; b = ws[f][k + 2];
        p2 = fmaf(a.x, b.x, fmaf(a.y, b.y, fmaf(a.z, b.z, fmaf(a.w, b.w, p2))));
        a = hs[il][k + 3]; b = ws[f][k + 3];
        p3 = fmaf(a.x, b.x, fmaf(a.y, b.y, fmaf(a.z, b.z, fmaf(a.w, b.w, p3))));
    }
    const float acc = (p0 + p1) + (p2 + p3);
    const int i = i0 + il;
    g[(size_t)i * DIM + bh * NHID + f] = acc;
    float sv = acc * attn_w[f];
    float dv = acc * attn_w[NHID + f];
#pragma unroll
    for (int off = 1; off <= 8; off <<= 1) {
        sv += __shfl_xor(sv, off, 64);
        dv += __shfl_xor(dv, off, 64);
    }
    if (f == 0) { srcv[i * NHEADS + bh] = sv; dstv[i * NHEADS + bh] = dv; }
}

// K2: 512 threads (8 waves), 4 rows/block, grid 256.
// LDS ~66 KB -> 2 blocks/CU: cross-block overlap at barriers (R1's win)
// + R=4 g-traffic halving (R2's win). 3 barriers; stats computed
// redundantly per-thread (removes the 36-thread serial phase + a barrier).
__global__ __launch_bounds__(512, 4) void fused_kernel(
    const int* __restrict__ adj, const float* __restrict__ s,
    const float* __restrict__ g, const float* __restrict__ srcv,
    const float* __restrict__ dstv, float* __restrict__ out)
{
    const int i0   = blockIdx.x * 4;
    const int tid  = threadIdx.x;
    const int lane = tid & 63;
    const int wv   = tid >> 6;            // wave 0..7

    __shared__ float evL[4][NNODES];          // 16 KB: adj ? exp(s) : 0
    __shared__ float dstL[NNODES * NHEADS];   // 32 KB staged dstv
    __shared__ float sh_src[4][NHEADS];
    __shared__ float zeA[8][NHEADS][4];       // 1 KB
    __shared__ float zsA[8][2];
    __shared__ float redO[8][4][NHEADS][4][4];  // 16 KB
    __shared__ float ztA[8][4][NHEADS];       // 1 KB

    // ---- Phase A1: ev into LDS; zs partials; stage dstv + srcv ----
    // k=0 covers rows {0,1}, k=1 rows {2,3}; per wave the row is uniform.
    float zs[2] = {0.f, 0.f};
#pragma unroll
    for (int k = 0; k < 2; k++) {
        const int idx = k * 512 + tid;    // 0..1023
        const int r   = idx >> 8;         // 0..3
        const int c   = idx & 255;
        const int4   a  = ((const int4*)  adj)[(size_t)(i0 + r) * (NNODES/4) + c];
        const float4 sv = ((const float4*)s  )[(size_t)(i0 + r) * (NNODES/4) + c];
        float4 e4;
        e4.x = a.x ? __expf(sv.x) : 0.f;
        e4.y = a.y ? __expf(sv.y) : 0.f;
        e4.z = a.z ? __expf(sv.z) : 0.f;
        e4.w = a.w ? __expf(sv.w) : 0.f;
        ((float4*)evL[r])[c] = e4;
        zs[k] += e4.x + e4.y + e4.z + e4.w;
    }
    {
        const float4* dv4 = (const float4*)dstv;
        float4* dl4 = (float4*)dstL;
#pragma unroll
        for (int k = 0; k < 4; k++) dl4[k * 512 + tid] = dv4[k * 512 + tid];
        if (tid < 32) sh_src[tid >> 3][tid & 7] =
            srcv[(size_t)(i0 + (tid >> 3)) * NHEADS + (tid & 7)];
    }
#pragma unroll
    for (int off = 1; off <= 32; off <<= 1) {
        zs[0] += __shfl_xor(zs[0], off, 64);
        zs[1] += __shfl_xor(zs[1], off, 64);
    }
    if (lane == 0) { zsA[wv][0] = zs[0]; zsA[wv][1] = zs[1]; }
    __syncthreads();                      // barrier 1

    // ---- Phase A2: ze[r][h] over unmasked j ----
    const int hA  = tid & 7;
    const int jsA = tid >> 3;             // 0..63
    float ze[4] = {0.f, 0.f, 0.f, 0.f};
    {
        const float sH[4] = { sh_src[0][hA], sh_src[1][hA],
                              sh_src[2][hA], sh_src[3][hA] };
#pragma unroll 4
        for (int t = 0; t < 16; t++) {
            const int j = t * 64 + jsA;
            const float d = dstL[j * NHEADS + hA];
#pragma unroll
            for (int r = 0; r < 4; r++) {
                float e = sH[r] + d;
                e = e > 0.f ? e : NEG_SLOPE * e;
                ze[r] += (evL[r][j] != 0.f) ? __expf(e) : 0.f;
            }
        }
    }
#pragma unroll
    for (int off = 8; off <= 32; off <<= 1)
#pragma unroll
        for (int r = 0; r < 4; r++) ze[r] += __shfl_xor(ze[r], off, 64);
    if (lane < NHEADS) {
#pragma unroll
        for (int r = 0; r < 4; r++) zeA[wv][lane][r] = ze[r];
    }
    __syncthreads();                      // barrier 2

    // ---- Phase B: tid = jsB*32 + hB*4 + qB ----
    const int qB  = tid & 3;
    const int hB  = (tid >> 2) & 7;
    const int jsB = tid >> 5;             // 0..15
    // redundant per-thread stats (broadcast LDS reads; removes a barrier)
    float ize[4], izs[4];
#pragma unroll
    for (int r = 0; r < 4; r++) {
        float z = 0.f;
#pragma unroll
        for (int w2 = 0; w2 < 8; w2++) z += zeA[w2][hB][r];
        ize[r] = 1.f / z;
        const int sl = r >> 1, b0 = (r & 1) * 4;
        izs[r] = 1.f / (zsA[b0][sl] + zsA[b0+1][sl] + zsA[b0+2][sl] + zsA[b0+3][sl]);
    }
    const float sB[4] = { sh_src[0][hB], sh_src[1][hB],
                          sh_src[2][hB], sh_src[3][hB] };

    float acc[4][4] = {{0.f,0.f,0.f,0.f},{0.f,0.f,0.f,0.f},
                       {0.f,0.f,0.f,0.f},{0.f,0.f,0.f,0.f}};
    float zt[4] = {0.f, 0.f, 0.f, 0.f};
    const float4* g4 = (const float4*)g;
    const int rowb0 = jsB * 4;            // + tg*64 (+K selects row)
    const int fq    = hB * 4 + qB;        // float4 slot within a row

#pragma unroll 2
    for (int tg = 0; tg < 16; tg++) {
        const int jw = tg * 64 + rowb0 + qB;
        const float d = dstL[jw * NHEADS + hB];
        float w[4];
#pragma unroll
        for (int r = 0; r < 4; r++) {
            float e = sB[r] + d;
            e = e > 0.f ? e : NEG_SLOPE * e;
            const float x  = __expf(e);
            const float ev = evL[r][jw];
            const float arg = (ev != 0.f) ? fmaf(x, ize[r], ev * izs[r]) : 0.f;
            w[r] = __expf(arg);           // exp(0)=1 at masked positions
            zt[r] += w[r];
        }
#define KSTEP(K, CTRL)                                                        \
        {                                                                     \
            const int j = tg * 64 + rowb0 + (K);                              \
            const float4 gv = g4[(size_t)j * 32 + fq];                        \
            const float wk0 = qbcast<CTRL>(w[0]);                             \
            const float wk1 = qbcast<CTRL>(w[1]);                             \
            const float wk2 = qbcast<CTRL>(w[2]);                             \
            const float wk3 = qbcast<CTRL>(w[3]);                             \
            acc[0][0] = fmaf(wk0, gv.x, acc[0][0]);                           \
            acc[0][1] = fmaf(wk0, gv.y, acc[0][1]);                           \
            acc[0][2] = fmaf(wk0, gv.z, acc[0][2]);                           \
            acc[0][3] = fmaf(wk0, gv.w, acc[0][3]);                           \
            acc[1][0] = fmaf(wk1, gv.x, acc[1][0]);                           \
            acc[1][1] = fmaf(wk1, gv.y, acc[1][1]);                           \
            acc[1][2] = fmaf(wk1, gv.z, acc[1][2]);                           \
            acc[1][3] = fmaf(wk1, gv.w, acc[1][3]);                           \
            acc[2][0] = fmaf(wk2, gv.x, acc[2][0]);                           \
            acc[2][1] = fmaf(wk2, gv.y, acc[2][1]);                           \
            acc[2][2] = fmaf(wk2, gv.z, acc[2][2]);                           \
            acc[2][3] = fmaf(wk2, gv.w, acc[2][3]);                           \
            acc[3][0] = fmaf(wk3, gv.x, acc[3][0]);                           \
            acc[3][1] = fmaf(wk3, gv.y, acc[3][1]);                           \
            acc[3][2] = fmaf(wk3, gv.z, acc[3][2]);                           \
            acc[3][3] = fmaf(wk3, gv.w, acc[3][3]);                           \
        }
        KSTEP(0, 0x00)
        KSTEP(1, 0x55)
        KSTEP(2, 0xAA)
        KSTEP(3, 0xFF)
#undef KSTEP
    }

    // ---- Epilogue ----
#pragma unroll
    for (int r = 0; r < 4; r++)
#pragma unroll
        for (int m = 0; m < 4; m++) acc[r][m] += __shfl_xor(acc[r][m], 32, 64);
#pragma unroll
    for (int r = 0; r < 4; r++) {
        zt[r] += __shfl_xor(zt[r], 1, 64);
        zt[r] += __shfl_xor(zt[r], 2, 64);
        zt[r] += __shfl_xor(zt[r], 32, 64);
    }
    if (lane < 32) {
#pragma unroll
        for (int r = 0; r < 4; r++)
            *(float4*)&redO[wv][r][hB][qB][0] =
                make_float4(acc[r][0], acc[r][1], acc[r][2], acc[r][3]);
        if ((lane & 3) == 0) {
#pragma unroll
            for (int r = 0; r < 4; r++) ztA[wv][r][hB] = zt[r];
        }
    }
    __syncthreads();                      // barrier 3
    {
        const int rr = tid >> 7;          // 0..3
        const int hf = tid & 127;
        const int oh = hf >> 4;
        const int qq = (hf >> 2) & 3;
        const int mm = hf & 3;
        float v = 0.f, z = 0.f;
#pragma unroll
        for (int w2 = 0; w2 < 8; w2++) {
            v += redO[w2][rr][oh][qq][mm];
            z += ztA[w2][rr][oh];
        }
        out[(size_t)(i0 + rr) * DIM + hf] = v / z;
    }
}

extern "C" void kernel_launch(void* const* d_in, const int* in_sizes, int n_in,
                              void* d_out, int out_size, void* d_ws, size_t ws_size,
                              hipStream_t stream) {
    const float* h      = (const float*)d_in[0];
    const int*   adj    = (const int*)  d_in[1];
    const float* s      = (const float*)d_in[2];
    const float* W      = (const float*)d_in[3];
    const float* attn_w = (const float*)d_in[4];
    float* out = (float*)d_out;

    float* g    = (float*)d_ws;                      // 1024*128
    float* srcv = g    + (size_t)NNODES * DIM;       // 1024*8
    float* dstv = srcv + (size_t)NNODES * NHEADS;    // 1024*8

    proj_kernel <<<512, 256, 0, stream>>>(h, W, attn_w, g, srcv, dstv);
    fused_kernel<<<NNODES / 4, 512, 0, stream>>>(adj, s, g, srcv, dstv, out);
}

// Round 4
// 83.809 us; speedup vs baseline: 1.0002x; 1.0002x over previous
//
#include <hip/hip_runtime.h>

#define NNODES 1024
#define NHEADS 8
#define NHID 16
#define DIM 128            // NHEADS * NHID
#define NEG_SLOPE 0.2f

// quad broadcast via DPP quad_perm
template<int CTRL>
__device__ __forceinline__ float qbcast(float v) {
    return __int_as_float(__builtin_amdgcn_mov_dpp(__float_as_int(v), CTRL, 0xF, 0xF, true));
}

// K1: g = h @ W^T tiled 16(i) x 16(one head); src/dst reductions fused.
__global__ __launch_bounds__(256) void proj_kernel(
    const float* __restrict__ h, const float* __restrict__ W,
    const float* __restrict__ attn_w,
    float* __restrict__ g, float* __restrict__ srcv, float* __restrict__ dstv)
{
    const int bi = blockIdx.x & 63;   // i-tile
    const int bh = blockIdx.x >> 6;   // head
    const int i0 = bi << 4;
    const int tid = threadIdx.x;
    __shared__ float4 hs[16][33];
    __shared__ float4 ws[16][33];
    const float4* h4 = (const float4*)h;   // 32 float4 per row
    const float4* W4 = (const float4*)W;
    {
        const int t0 = tid, t1 = tid + 256;
        hs[t0 >> 5][t0 & 31] = h4[(size_t)i0 * 32 + t0];
        hs[t1 >> 5][t1 & 31] = h4[(size_t)i0 * 32 + t1];
        ws[t0 >> 5][t0 & 31] = W4[(size_t)(bh * 16) * 32 + t0];
        ws[t1 >> 5][t1 & 31] = W4[(size_t)(bh * 16) * 32 + t1];
    }
    __syncthreads();
    const int il = tid >> 4;          // 0..15 local row
    const int f  = tid & 15;          // 0..15 feature within head
    float p0 = 0.f, p1 = 0.f, p2 = 0.f, p3 = 0.f;
#pragma unroll
    for (int k = 0; k < 32; k += 4) {
        float4 a, b;
        a = hs[il][k];     b = ws[f][k];
        p0 = fmaf(a.x, b.x, fmaf(a.y, b.y, fmaf(a.z, b.z, fmaf(a.w, b.w, p0))));
        a = hs[il][k + 1]; b = ws[f][k + 1];
        p1 = fmaf(a.x, b.x, fmaf(a.y, b.y, fmaf(a.z, b.z, fmaf(a.w, b.w, p1))));
        a = hs[il][k + 2]; b = ws[f][k + 2];
        p2 = fmaf(a.x, b.x, fmaf(a.y, b.y, fmaf(a.z, b.z, fmaf(a.w, b.w, p2))));
        a = hs[il][k + 3]; b = ws[f][k + 3];
        p3 = fmaf(a.x, b.x, fmaf(a.y, b.y, fmaf(a.z, b.z, fmaf(a.w, b.w, p3))));
    }
    const float acc = (p0 + p1) + (p2 + p3);
    const int i = i0 + il;
    g[(size_t)i * DIM + bh * NHID + f] = acc;
    float sv = acc * attn_w[f];
    float dv = acc * attn_w[NHID + f];
#pragma unroll
    for (int off = 1; off <= 8; off <<= 1) {
        sv += __shfl_xor(sv, off, 64);
        dv += __shfl_xor(dv, off, 64);
    }
    if (f == 0) { srcv[i * NHEADS + bh] = sv; dstv[i * NHEADS + bh] = dv; }
}

// K2: R1 config (R=2 rows, 512 threads, grid 512 -> 4096 waves, 2 blocks/CU)
// with A1+A2 merged into ONE pass (ze computed from in-register ev + coalesced
// global dst reads) -> 2 barriers total; conflict-free Phase-B lane map.
__global__ __launch_bounds__(512, 4) void fused_kernel(
    const int* __restrict__ adj, const float* __restrict__ s,
    const float* __restrict__ g, const float* __restrict__ srcv,
    const float* __restrict__ dstv, float* __restrict__ out)
{
    const int i0   = blockIdx.x * 2;
    const int tid  = threadIdx.x;
    const int lane = tid & 63;
    const int wv   = tid >> 6;            // wave 0..7

    __shared__ float evL[2][NNODES];          // 8 KB: adj ? exp(s) : 0
    __shared__ float dstL[NNODES * NHEADS];   // 32 KB staged dstv
    __shared__ float sh_src[2][NHEADS];
    __shared__ float zeA[8][NHEADS];          // per-wave partial (wave's own r)
    __shared__ float zsA[8];
    __shared__ float redO[8][2][NHEADS][4][4];  // 8 KB
    __shared__ float ztA[8][2][NHEADS];

    // ---- Phase A (merged): r = tid>>8 (waves 0-3 -> r0, 4-7 -> r1) ----
    const int rA = tid >> 8;
    const int cA = tid & 255;             // int4/float4 column = j-quad
    {
        const float4* dv4 = (const float4*)dstv;
        float4* dl4 = (float4*)dstL;
#pragma unroll
        for (int k = 0; k < 4; k++) dl4[k * 512 + tid] = dv4[k * 512 + tid];
        if (tid < 16) sh_src[tid >> 3][tid & 7] =
            srcv[(size_t)(i0 + (tid >> 3)) * NHEADS + (tid & 7)];
    }
    float evj[4];
    float zs;
    {
        const int4   a  = ((const int4*)  adj)[(size_t)(i0 + rA) * (NNODES/4) + cA];
        const float4 sv = ((const float4*)s  )[(size_t)(i0 + rA) * (NNODES/4) + cA];
        evj[0] = a.x ? __expf(sv.x) : 0.f;
        evj[1] = a.y ? __expf(sv.y) : 0.f;
        evj[2] = a.z ? __expf(sv.z) : 0.f;
        evj[3] = a.w ? __expf(sv.w) : 0.f;
        ((float4*)evL[rA])[cA] = make_float4(evj[0], evj[1], evj[2], evj[3]);
        zs = (evj[0] + evj[1]) + (evj[2] + evj[3]);
    }
    // src[i0+rA][h]: broadcast loads
    float srcR[NHEADS];
    {
        const float4 s0 = ((const float4*)srcv)[(size_t)(i0 + rA) * 2 + 0];
        const float4 s1 = ((const float4*)srcv)[(size_t)(i0 + rA) * 2 + 1];
        srcR[0]=s0.x; srcR[1]=s0.y; srcR[2]=s0.z; srcR[3]=s0.w;
        srcR[4]=s1.x; srcR[5]=s1.y; srcR[6]=s1.z; srcR[7]=s1.w;
    }
    // ze[h] contributions for this thread's 4 j's (ev in registers = mask)
    float ze[NHEADS] = {0.f,0.f,0.f,0.f,0.f,0.f,0.f,0.f};
    {
        const float4* dv4 = (const float4*)dstv;
#pragma unroll
        for (int jj = 0; jj < 4; jj++) {
            const int j = 4 * cA + jj;
            const float4 d0 = dv4[(size_t)j * 2 + 0];
            const float4 d1 = dv4[(size_t)j * 2 + 1];
            const float dh[8] = {d0.x,d0.y,d0.z,d0.w,d1.x,d1.y,d1.z,d1.w};
            const bool live = (evj[jj] != 0.f);
#pragma unroll
            for (int hh = 0; hh < 8; hh++) {
                float e = srcR[hh] + dh[hh];
                e = e > 0.f ? e : NEG_SLOPE * e;
                ze[hh] += live ? __expf(e) : 0.f;
            }
        }
    }
#pragma unroll
    for (int off = 1; off <= 32; off <<= 1) {
        zs += __shfl_xor(zs, off, 64);
#pragma unroll
        for (int hh = 0; hh < 8; hh++) ze[hh] += __shfl_xor(ze[hh], off, 64);
    }
    if (lane == 0) {
        zsA[wv] = zs;
#pragma unroll
        for (int hh = 0; hh < 8; hh++) zeA[wv][hh] = ze[hh];
    }
    __syncthreads();                      // barrier 1 (only pre-B barrier)

    // ---- Phase B: tid = jsB*32 + hB*4 + qB ----
    const int qB  = tid & 3;
    const int hB  = (tid >> 2) & 7;
    const int jsB = tid >> 5;             // 0..15
    float ize[2], izs[2];
#pragma unroll
    for (int r = 0; r < 2; r++) {
        const int w0 = r * 4;
        ize[r] = 1.f / (zeA[w0][hB] + zeA[w0+1][hB] + zeA[w0+2][hB] + zeA[w0+3][hB]);
        izs[r] = 1.f / (zsA[w0] + zsA[w0+1] + zsA[w0+2] + zsA[w0+3]);
    }
    const float sB[2] = { sh_src[0][hB], sh_src[1][hB] };

    float acc0[4] = {0.f,0.f,0.f,0.f};
    float acc1[4] = {0.f,0.f,0.f,0.f};
    float zt0 = 0.f, zt1 = 0.f;
    const float4* g4 = (const float4*)g;
    const int rowb0 = jsB * 4;            // + tg*64 (+K selects row)
    const int fq    = hB * 4 + qB;        // float4 slot within a row

#pragma unroll 2
    for (int tg = 0; tg < 16; tg++) {
        const int jw = tg * 64 + rowb0 + qB;
        const float d = dstL[jw * NHEADS + hB];
        float e0 = sB[0] + d; e0 = e0 > 0.f ? e0 : NEG_SLOPE * e0;
        float e1 = sB[1] + d; e1 = e1 > 0.f ? e1 : NEG_SLOPE * e1;
        const float x0 = __expf(e0), x1 = __expf(e1);
        const float ev0 = evL[0][jw], ev1 = evL[1][jw];
        const float a0 = (ev0 != 0.f) ? fmaf(x0, ize[0], ev0 * izs[0]) : 0.f;
        const float a1 = (ev1 != 0.f) ? fmaf(x1, ize[1], ev1 * izs[1]) : 0.f;
        const float w0 = __expf(a0), w1 = __expf(a1);   // exp(0)=1 at masked
        zt0 += w0; zt1 += w1;

#define KSTEP(K, CTRL)                                                        \
        {                                                                     \
            const int j = tg * 64 + rowb0 + (K);                              \
            const float4 gv = g4[(size_t)j * 32 + fq];                        \
            const float wk0 = qbcast<CTRL>(w0);                               \
            const float wk1 = qbcast<CTRL>(w1);                               \
            acc0[0] = fmaf(wk0, gv.x, acc0[0]);                               \
            acc0[1] = fmaf(wk0, gv.y, acc0[1]);                               \
            acc0[2] = fmaf(wk0, gv.z, acc0[2]);                               \
            acc0[3] = fmaf(wk0, gv.w, acc0[3]);                               \
            acc1[0] = fmaf(wk1, gv.x, acc1[0]);                               \
            acc1[1] = fmaf(wk1, gv.y, acc1[1]);                               \
            acc1[2] = fmaf(wk1, gv.z, acc1[2]);                               \
            acc1[3] = fmaf(wk1, gv.w, acc1[3]);                               \
        }
        KSTEP(0, 0x00)
        KSTEP(1, 0x55)
        KSTEP(2, 0xAA)
        KSTEP(3, 0xFF)
#undef KSTEP
    }

    // ---- Epilogue ----
#pragma unroll
    for (int m = 0; m < 4; m++) {
        acc0[m] += __shfl_xor(acc0[m], 32, 64);   // reduce jsB bit inside wave
        acc1[m] += __shfl_xor(acc1[m], 32, 64);
    }
    zt0 += __shfl_xor(zt0, 1, 64); zt0 += __shfl_xor(zt0, 2, 64); zt0 += __shfl_xor(zt0, 32, 64);
    zt1 += __shfl_xor(zt1, 1, 64); zt1 += __shfl_xor(zt1, 2, 64); zt1 += __shfl_xor(zt1, 32, 64);
    if (lane < 32) {
        *(float4*)&redO[wv][0][hB][qB][0] = make_float4(acc0[0], acc0[1], acc0[2], acc0[3]);
        *(float4*)&redO[wv][1][hB][qB][0] = make_float4(acc1[0], acc1[1], acc1[2], acc1[3]);
        if ((lane & 3) == 0) { ztA[wv][0][hB] = zt0; ztA[wv][1][hB] = zt1; }
    }
    __syncthreads();                      // barrier 2
    if (tid < 256) {
        const int rr = tid >> 7;
        const int hf = tid & 127;
        const int oh = hf >> 4;
        const int qq = (hf >> 2) & 3;
        const int mm = hf & 3;
        float v = 0.f, z = 0.f;
#pragma unroll
        for (int w2 = 0; w2 < 8; w2++) {
            v += redO[w2][rr][oh][qq][mm];
            z += ztA[w2][rr][oh];
        }
        out[(size_t)(i0 + rr) * DIM + hf] = v / z;
    }
}

extern "C" void kernel_launch(void* const* d_in, const int* in_sizes, int n_in,
                              void* d_out, int out_size, void* d_ws, size_t ws_size,
                              hipStream_t stream) {
    const float* h      = (const float*)d_in[0];
    const int*   adj    = (const int*)  d_in[1];
    const float* s      = (const float*)d_in[2];
    const float* W      = (const float*)d_in[3];
    const float* attn_w = (const float*)d_in[4];
    float* out = (float*)d_out;

    float* g    = (float*)d_ws;                      // 1024*128
    float* srcv = g    + (size_t)NNODES * DIM;       // 1024*8
    float* dstv = srcv + (size_t)NNODES * NHEADS;    // 1024*8

    proj_kernel <<<512, 256, 0, stream>>>(h, W, attn_w, g, srcv, dstv);
    fused_kernel<<<NNODES / 2, 512, 0, stream>>>(adj, s, g, srcv, dstv, out);
}

// Round 5
// 82.370 us; speedup vs baseline: 1.0177x; 1.0175x over previous
//
#include <hip/hip_runtime.h>

#define NNODES 1024
#define NHEADS 8
#define NHID 16
#define DIM 128            // NHEADS * NHID
#define NEG_SLOPE 0.2f

// quad broadcast via DPP quad_perm
template<int CTRL>
__device__ __forceinline__ float qbcast(float v) {
    return __int_as_float(__builtin_amdgcn_mov_dpp(__float_as_int(v), CTRL, 0xF, 0xF, true));
}

// K1: g = h @ W^T tiled 16(i) x 16(one head); src/dst reductions fused.
__global__ __launch_bounds__(256) void proj_kernel(
    const float* __restrict__ h, const float* __restrict__ W,
    const float* __restrict__ attn_w,
    float* __restrict__ g, float* __restrict__ srcv, float* __restrict__ dstv)
{
    const int bi = blockIdx.x & 63;   // i-tile
    const int bh = blockIdx.x >> 6;   // head
    const int i0 = bi << 4;
    const int tid = threadIdx.x;
    __shared__ float4 hs[16][33];
    __shared__ float4 ws[16][33];
    const float4* h4 = (const float4*)h;   // 32 float4 per row
    const float4* W4 = (const float4*)W;
    {
        const int t0 = tid, t1 = tid + 256;
        hs[t0 >> 5][t0 & 31] = h4[(size_t)i0 * 32 + t0];
        hs[t1 >> 5][t1 & 31] = h4[(size_t)i0 * 32 + t1];
        ws[t0 >> 5][t0 & 31] = W4[(size_t)(bh * 16) * 32 + t0];
        ws[t1 >> 5][t1 & 31] = W4[(size_t)(bh * 16) * 32 + t1];
    }
    __syncthreads();
    const int il = tid >> 4;          // 0..15 local row
    const int f  = tid & 15;          // 0..15 feature within head
    float p0 = 0.f, p1 = 0.f, p2 = 0.f, p3 = 0.f;
#pragma unroll
    for (int k = 0; k < 32; k += 4) {
        float4 a, b;
        a = hs[il][k];     b = ws[f][k];
        p0 = fmaf(a.x, b.x, fmaf(a.y, b.y, fmaf(a.z, b.z, fmaf(a.w, b.w, p0))));
        a = hs[il][k + 1]; b = ws[f][k + 1];
        p1 = fmaf(a.x, b.x, fmaf(a.y, b.y, fmaf(a.z, b.z, fmaf(a.w, b.w, p1))));
        a = hs[il][k + 2]; b = ws[f][k + 2];
        p2 = fmaf(a.x, b.x, fmaf(a.y, b.y, fmaf(a.z, b.z, fmaf(a.w, b.w, p2))));
        a = hs[il][k + 3]; b = ws[f][k + 3];
        p3 = fmaf(a.x, b.x, fmaf(a.y, b.y, fmaf(a.z, b.z, fmaf(a.w, b.w, p3))));
    }
    const float acc = (p0 + p1) + (p2 + p3);
    const int i = i0 + il;
    g[(size_t)i * DIM + bh * NHID + f] = acc;
    float sv = acc * attn_w[f];
    float dv = acc * attn_w[NHID + f];
#pragma unroll
    for (int off = 1; off <= 8; off <<= 1) {
        sv += __shfl_xor(sv, off, 64);
        dv += __shfl_xor(dv, off, 64);
    }
    if (f == 0) { srcv[i * NHEADS + bh] = sv; dstv[i * NHEADS + bh] = dv; }
}

// K2: R1 structure, but NO dstv LDS staging -> LDS 49 KB -> ~17.5 KB.
// dstv (32 KB, read-only, L2-resident) is read directly from global in A2/B;
// both patterns are 256 B/wave coalesced. 4 blocks/CU = 32 waves/CU =
// 8 waves/SIMD (HW max); launch_bounds(512,8) caps VGPR at 64.
__global__ __launch_bounds__(512, 8) void fused_kernel(
    const int* __restrict__ adj, const float* __restrict__ s,
    const float* __restrict__ g, const float* __restrict__ srcv,
    const float* __restrict__ dstv, float* __restrict__ out)
{
    const int i0   = blockIdx.x * 2;
    const int tid  = threadIdx.x;
    const int lane = tid & 63;
    const int wv   = tid >> 6;            // wave 0..7

    __shared__ float evL[2][NNODES];          // 8 KB: adj ? exp(s) : 0
    __shared__ float sh_src[2][NHEADS];
    __shared__ float zeA[8][NHEADS][2];       // 512 B
    __shared__ float zsA[8];
    __shared__ float redO[8][2][NHEADS][4][4];  // 8 KB
    __shared__ float ztA[8][2][NHEADS];       // 512 B

    // ---- Phase A1: ev into LDS; zs partial ----
    const int rA = tid >> 8;              // waves 0-3 -> row 0, 4-7 -> row 1
    const int cA = tid & 255;
    float zs;
    {
        const int4   a  = ((const int4*)  adj)[(size_t)(i0 + rA) * (NNODES/4) + cA];
        const float4 sv = ((const float4*)s  )[(size_t)(i0 + rA) * (NNODES/4) + cA];
        float4 e4;
        e4.x = a.x ? __expf(sv.x) : 0.f;
        e4.y = a.y ? __expf(sv.y) : 0.f;
        e4.z = a.z ? __expf(sv.z) : 0.f;
        e4.w = a.w ? __expf(sv.w) : 0.f;
        ((float4*)evL[rA])[cA] = e4;
        zs = (e4.x + e4.y) + (e4.z + e4.w);
    }
    if (tid < 16) sh_src[tid >> 3][tid & 7] =
        srcv[(size_t)(i0 + (tid >> 3)) * NHEADS + (tid & 7)];
#pragma unroll
    for (int off = 1; off <= 32; off <<= 1) zs += __shfl_xor(zs, off, 64);
    if (lane == 0) zsA[wv] = zs;          // wave's row = rA (uniform per wave)
    __syncthreads();                      // barrier 1

    // ---- Phase A2: ze[r][h]; dst straight from global (coalesced L2 hits) ----
    const int hA  = tid & 7;
    const int jsA = tid >> 3;             // 0..63
    float ze0 = 0.f, ze1 = 0.f;
    {
        const float sH0 = sh_src[0][hA], sH1 = sh_src[1][hA];
#pragma unroll 2
        for (int t = 0; t < 16; t++) {
            const int j = t * 64 + jsA;
            const float d = dstv[j * NHEADS + hA];
            float e0 = sH0 + d; e0 = e0 > 0.f ? e0 : NEG_SLOPE * e0;
            float e1 = sH1 + d; e1 = e1 > 0.f ? e1 : NEG_SLOPE * e1;
            ze0 += (evL[0][j] != 0.f) ? __expf(e0) : 0.f;
            ze1 += (evL[1][j] != 0.f) ? __expf(e1) : 0.f;
        }
    }
#pragma unroll
    for (int off = 8; off <= 32; off <<= 1) {
        ze0 += __shfl_xor(ze0, off, 64);
        ze1 += __shfl_xor(ze1, off, 64);
    }
    if (lane < NHEADS) { zeA[wv][lane][0] = ze0; zeA[wv][lane][1] = ze1; }
    __syncthreads();                      // barrier 2

    // ---- Phase B: tid = jsB*32 + hB*4 + qB ----
    const int qB  = tid & 3;
    const int hB  = (tid >> 2) & 7;
    const int jsB = tid >> 5;             // 0..15
    float ize[2], izs[2];
    {
        float z0 = 0.f, z1 = 0.f;
#pragma unroll
        for (int w2 = 0; w2 < 8; w2++) { z0 += zeA[w2][hB][0]; z1 += zeA[w2][hB][1]; }
        ize[0] = 1.f / z0; ize[1] = 1.f / z1;
        izs[0] = 1.f / (zsA[0] + zsA[1] + zsA[2] + zsA[3]);
        izs[1] = 1.f / (zsA[4] + zsA[5] + zsA[6] + zsA[7]);
    }
    const float sB0 = sh_src[0][hB], sB1 = sh_src[1][hB];

    float acc0[4] = {0.f,0.f,0.f,0.f};
    float acc1[4] = {0.f,0.f,0.f,0.f};
    float zt0 = 0.f, zt1 = 0.f;
    const float4* g4 = (const float4*)g;
    const int rowb0 = jsB * 4;            // + tg*64 (+K selects row)
    const int fq    = hB * 4 + qB;        // float4 slot within a row

#pragma unroll 1
    for (int tg = 0; tg < 16; tg++) {
        const int jw = tg * 64 + rowb0 + qB;
        const float d = dstv[jw * NHEADS + hB];   // global, 256 B/wave coalesced
        float e0 = sB0 + d; e0 = e0 > 0.f ? e0 : NEG_SLOPE * e0;
        float e1 = sB1 + d; e1 = e1 > 0.f ? e1 : NEG_SLOPE * e1;
        const float x0 = __expf(e0), x1 = __expf(e1);
        const float ev0 = evL[0][jw], ev1 = evL[1][jw];
        const float a0 = (ev0 != 0.f) ? fmaf(x0, ize[0], ev0 * izs[0]) : 0.f;
        const float a1 = (ev1 != 0.f) ? fmaf(x1, ize[1], ev1 * izs[1]) : 0.f;
        const float w0 = __expf(a0), w1 = __expf(a1);   // exp(0)=1 at masked
        zt0 += w0; zt1 += w1;

#define KSTEP(K, CTRL)                                                        \
        {                                                                     \
            const int j = tg * 64 + rowb0 + (K);                              \
            const float4 gv = g4[(size_t)j * 32 + fq];                        \
            const float wk0 = qbcast<CTRL>(w0);                               \
            const float wk1 = qbcast<CTRL>(w1);                               \
            acc0[0] = fmaf(wk0, gv.x, acc0[0]);                               \
            acc0[1] = fmaf(wk0, gv.y, acc0[1]);                               \
            acc0[2] = fmaf(wk0, gv.z, acc0[2]);                               \
            acc0[3] = fmaf(wk0, gv.w, acc0[3]);                               \
            acc1[0] = fmaf(wk1, gv.x, acc1[0]);                               \
            acc1[1] = fmaf(wk1, gv.y, acc1[1]);                               \
            acc1[2] = fmaf(wk1, gv.z, acc1[2]);                               \
            acc1[3] = fmaf(wk1, gv.w, acc1[3]);                               \
        }
        KSTEP(0, 0x00)
        KSTEP(1, 0x55)
        KSTEP(2, 0xAA)
        KSTEP(3, 0xFF)
#undef KSTEP
    }

    // ---- Epilogue ----
#pragma unroll
    for (int m = 0; m < 4; m++) {
        acc0[m] += __shfl_xor(acc0[m], 32, 64);   // reduce jsB bit inside wave
        acc1[m] += __shfl_xor(acc1[m], 32, 64);
    }
    zt0 += __shfl_xor(zt0, 1, 64); zt0 += __shfl_xor(zt0, 2, 64); zt0 += __shfl_xor(zt0, 32, 64);
    zt1 += __shfl_xor(zt1, 1, 64); zt1 += __shfl_xor(zt1, 2, 64); zt1 += __shfl_xor(zt1, 32, 64);
    if (lane < 32) {
        *(float4*)&redO[wv][0][hB][qB][0] = make_float4(acc0[0], acc0[1], acc0[2], acc0[3]);
        *(float4*)&redO[wv][1][hB][qB][0] = make_float4(acc1[0], acc1[1], acc1[2], acc1[3]);
        if ((lane & 3) == 0) { ztA[wv][0][hB] = zt0; ztA[wv][1][hB] = zt1; }
    }
    __syncthreads();                      // barrier 3
    if (tid < 256) {
        const int rr = tid >> 7;
        const int hf = tid & 127;
        const int oh = hf >> 4;
        const int qq = (hf >> 2) & 3;
        const int mm = hf & 3;
        float v = 0.f, z = 0.f;
#pragma unroll
        for (int w2 = 0; w2 < 8; w2++) {
            v += redO[w2][rr][oh][qq][mm];
            z += ztA[w2][rr][oh];
        }
        out[(size_t)(i0 + rr) * DIM + hf] = v / z;
    }
}

extern "C" void kernel_launch(void* const* d_in, const int* in_sizes, int n_in,
                              void* d_out, int out_size, void* d_ws, size_t ws_size,
                              hipStream_t stream) {
    const float* h      = (const float*)d_in[0];
    const int*   adj    = (const int*)  d_in[1];
    const float* s      = (const float*)d_in[2];
    const float* W      = (const float*)d_in[3];
    const float* attn_w = (const float*)d_in[4];
    float* out = (float*)d_out;

    float* g    = (float*)d_ws;                      // 1024*128
    float* srcv = g    + (size_t)NNODES * DIM;       // 1024*8
    float* dstv = srcv + (size_t)NNODES * NHEADS;    // 1024*8

    proj_kernel <<<512, 256, 0, stream>>>(h, W, attn_w, g, srcv, dstv);
    fused_kernel<<<NNODES / 2, 512, 0, stream>>>(adj, s, g, srcv, dstv, out);
}

// Round 6
// 81.627 us; speedup vs baseline: 1.0270x; 1.0091x over previous
//
#include <hip/hip_runtime.h>

#define NNODES 1024
#define NHEADS 8
#define NHID 16
#define DIM 128            // NHEADS * NHID
#define NEG_SLOPE 0.2f

// quad broadcast via DPP quad_perm
template<int CTRL>
__device__ __forceinline__ float qbcast(float v) {
    return __int_as_float(__builtin_amdgcn_mov_dpp(__float_as_int(v), CTRL, 0xF, 0xF, true));
}

// async global->LDS, 16B per lane; ldst must be wave-uniform base (HW writes
// base + lane*16), gsrc is per-lane.
__device__ __forceinline__ void async_cp16(const float4* gsrc, float4* ldst) {
    __builtin_amdgcn_global_load_lds(
        (const __attribute__((address_space(1))) void*)gsrc,
        (__attribute__((address_space(3))) void*)ldst, 16, 0, 0);
}

// K1: g = h @ W^T tiled 16(i) x 16(one head); src/dst reductions fused.
// 4 independent FMA chains (1 x 128-deep chain exposes ~512cy at 2 waves/SIMD).
__global__ __launch_bounds__(256) void proj_kernel(
    const float* __restrict__ h, const float* __restrict__ W,
    const float* __restrict__ attn_w,
    float* __restrict__ g, float* __restrict__ srcv, float* __restrict__ dstv)
{
    const int bi = blockIdx.x & 63;   // i-tile
    const int bh = blockIdx.x >> 6;   // head
    const int i0 = bi << 4;
    const int tid = threadIdx.x;
    __shared__ float4 hs[16][33];
    __shared__ float4 ws[16][33];
    const float4* h4 = (const float4*)h;   // 32 float4 per row
    const float4* W4 = (const float4*)W;
    {
        const int t0 = tid, t1 = tid + 256;
        hs[t0 >> 5][t0 & 31] = h4[(size_t)i0 * 32 + t0];
        hs[t1 >> 5][t1 & 31] = h4[(size_t)i0 * 32 + t1];
        ws[t0 >> 5][t0 & 31] = W4[(size_t)(bh * 16) * 32 + t0];
        ws[t1 >> 5][t1 & 31] = W4[(size_t)(bh * 16) * 32 + t1];
    }
    __syncthreads();
    const int il = tid >> 4;          // 0..15 local row
    const int f  = tid & 15;          // 0..15 feature within head
    float p0 = 0.f, p1 = 0.f, p2 = 0.f, p3 = 0.f;
#pragma unroll
    for (int k = 0; k < 32; k += 4) {
        float4 a, b;
        a = hs[il][k];     b = ws[f][k];
        p0 = fmaf(a.x, b.x, fmaf(a.y, b.y, fmaf(a.z, b.z, fmaf(a.w, b.w, p0))));
        a = hs[il][k + 1]; b = ws[f][k + 1];
        p1 = fmaf(a.x, b.x, fmaf(a.y, b.y, fmaf(a.z, b.z, fmaf(a.w, b.w, p1))));
        a = hs[il][k + 2]; b = ws[f][k + 2];
        p2 = fmaf(a.x, b.x, fmaf(a.y, b.y, fmaf(a.z, b.z, fmaf(a.w, b.w, p2))));
        a = hs[il][k + 3]; b = ws[f][k + 3];
        p3 = fmaf(a.x, b.x, fmaf(a.y, b.y, fmaf(a.z, b.z, fmaf(a.w, b.w, p3))));
    }
    const float acc = (p0 + p1) + (p2 + p3);
    const int i = i0 + il;
    g[(size_t)i * DIM + bh * NHID + f] = acc;
    float sv = acc * attn_w[f];
    float dv = acc * attn_w[NHID + f];
#pragma unroll
    for (int off = 1; off <= 8; off <<= 1) {
        sv += __shfl_xor(sv, off, 64);
        dv += __shfl_xor(dv, off, 64);
    }
    if (f == 0) { srcv[i * NHEADS + bh] = sv; dstv[i * NHEADS + bh] = dv; }
}

// K2: byte-exact R1 structure (R=2, 512 thr, grid 512, dstL staged, 4 barriers,
// unroll-2 Phase B) except the dstL stage is async global_load_lds issued at
// the top of A1 (no VGPR round-trip; drains under A1's loads + exp work).
__global__ __launch_bounds__(512, 4) void fused_kernel(
    const int* __restrict__ adj, const float* __restrict__ s,
    const float* __restrict__ g, const float* __restrict__ srcv,
    const float* __restrict__ dstv, float* __restrict__ out)
{
    const int i0   = blockIdx.x * 2;
    const int tid  = threadIdx.x;
    const int lane = tid & 63;
    const int wv   = tid >> 6;            // wave 0..7

    __shared__ float evL[2][NNODES];          // 8 KB: adj ? exp(s) : 0
    __shared__ float dstL[NNODES * NHEADS];   // 32 KB staged dstv
    __shared__ float sh_src[2][NHEADS];
    __shared__ float zeA[8][NHEADS][2];
    __shared__ float zsA[8];
    __shared__ float statE[2][NHEADS];
    __shared__ float statS[2];
    __shared__ float redO[8][2][NHEADS][4][4];  // 8 KB
    __shared__ float ztA[8][2][NHEADS];

    // ---- Phase A1 ----
    // 1) issue async dstv -> dstL stage FIRST (latency hides under A1)
    {
        const float4* dv4 = (const float4*)dstv;
        float4* dl4 = (float4*)dstL;
        const int wb = wv << 6;           // wave-uniform base (64 float4/wave)
#pragma unroll
        for (int k = 0; k < 4; k++)
            async_cp16(dv4 + k * 512 + tid, dl4 + k * 512 + wb);
    }
    if (tid < 16) sh_src[tid >> 3][tid & 7] =
        srcv[(size_t)(i0 + (tid >> 3)) * NHEADS + (tid & 7)];
    // 2) ev = adj ? exp(s) : 0 into LDS; zs partial
    const int rA = tid >> 8;              // waves 0-3 -> row 0, 4-7 -> row 1
    const int cA = tid & 255;
    float zs;
    {
        const int4   a  = ((const int4*)  adj)[(size_t)(i0 + rA) * (NNODES/4) + cA];
        const float4 sv = ((const float4*)s  )[(size_t)(i0 + rA) * (NNODES/4) + cA];
        float4 e4;
        e4.x = a.x ? __expf(sv.x) : 0.f;
        e4.y = a.y ? __expf(sv.y) : 0.f;
        e4.z = a.z ? __expf(sv.z) : 0.f;
        e4.w = a.w ? __expf(sv.w) : 0.f;
        ((float4*)evL[rA])[cA] = e4;
        zs = (e4.x + e4.y) + (e4.z + e4.w);
    }
#pragma unroll
    for (int off = 1; off <= 32; off <<= 1) zs += __shfl_xor(zs, off, 64);
    if (lane == 0) zsA[wv] = zs;          // wave's row = rA (uniform per wave)
    __syncthreads();                      // barrier 1 (drains async stage too)

    // ---- Phase A2: ze[r][h] over unmasked j (dstL now valid) ----
    const int hA  = tid & 7;
    const int jsA = tid >> 3;             // 0..63
    float ze0 = 0.f, ze1 = 0.f;
    {
        const float sH0 = sh_src[0][hA], sH1 = sh_src[1][hA];
#pragma unroll 4
        for (int t = 0; t < 16; t++) {
            const int j = t * 64 + jsA;
            const float d = dstL[j * NHEADS + hA];
            float e0 = sH0 + d; e0 = e0 > 0.f ? e0 : NEG_SLOPE * e0;
            float e1 = sH1 + d; e1 = e1 > 0.f ? e1 : NEG_SLOPE * e1;
            ze0 += (evL[0][j] != 0.f) ? __expf(e0) : 0.f;
            ze1 += (evL[1][j] != 0.f) ? __expf(e1) : 0.f;
        }
    }
#pragma unroll
    for (int off = 8; off <= 32; off <<= 1) {
        ze0 += __shfl_xor(ze0, off, 64);
        ze1 += __shfl_xor(ze1, off, 64);
    }
    if (lane < NHEADS) { zeA[wv][lane][0] = ze0; zeA[wv][lane][1] = ze1; }
    __syncthreads();                      // barrier 2
    if (tid < 16) {
        const int hh = tid & 7, rr = tid >> 3;
        float z = 0.f;
#pragma unroll
        for (int w2 = 0; w2 < 8; w2++) z += zeA[w2][hh][rr];
        statE[rr][hh] = 1.f / z;
    } else if (tid < 18) {
        const int rr = tid - 16;
        statS[rr] = 1.f / (zsA[rr*4] + zsA[rr*4+1] + zsA[rr*4+2] + zsA[rr*4+3]);
    }
    __syncthreads();                      // barrier 3

    // ---- Phase B: tid = jsB*32 + hB*4 + qB ----
    const int qB  = tid & 3;
    const int hB  = (tid >> 2) & 7;
    const int jsB = tid >> 5;             // 0..15
    const float ize0 = statE[0][hB], ize1 = statE[1][hB];
    const float izs0 = statS[0],     izs1 = statS[1];
    const float sB0  = sh_src[0][hB], sB1 = sh_src[1][hB];

    float acc0[4] = {0.f,0.f,0.f,0.f};
    float acc1[4] = {0.f,0.f,0.f,0.f};
    float zt0 = 0.f, zt1 = 0.f;
    const float4* g4 = (const float4*)g;
    const int rowb0 = jsB * 4;            // + tg*64 (+K selects row)
    const int fq    = hB * 4 + qB;        // float4 slot within a row

#pragma unroll 2
    for (int tg = 0; tg < 16; tg++) {
        const int jw = tg * 64 + rowb0 + qB;
        const float d = dstL[jw * NHEADS + hB];
        float e0 = sB0 + d; e0 = e0 > 0.f ? e0 : NEG_SLOPE * e0;
        float e1 = sB1 + d; e1 = e1 > 0.f ? e1 : NEG_SLOPE * e1;
        const float x0 = __expf(e0), x1 = __expf(e1);
        const float ev0 = evL[0][jw], ev1 = evL[1][jw];
        const float a0 = (ev0 != 0.f) ? fmaf(x0, ize0, ev0 * izs0) : 0.f;
        const float a1 = (ev1 != 0.f) ? fmaf(x1, ize1, ev1 * izs1) : 0.f;
        const float w0 = __expf(a0), w1 = __expf(a1);   // exp(0)=1 at masked
        zt0 += w0; zt1 += w1;

#define KSTEP(K, CTRL)                                                        \
        {                                                                     \
            const int j = tg * 64 + rowb0 + (K);                              \
            const float4 gv = g4[(size_t)j * 32 + fq];                        \
            const float wk0 = qbcast<CTRL>(w0);                               \
            const float wk1 = qbcast<CTRL>(w1);                               \
            acc0[0] = fmaf(wk0, gv.x, acc0[0]);                               \
            acc0[1] = fmaf(wk0, gv.y, acc0[1]);                               \
            acc0[2] = fmaf(wk0, gv.z, acc0[2]);                               \
            acc0[3] = fmaf(wk0, gv.w, acc0[3]);                               \
            acc1[0] = fmaf(wk1, gv.x, acc1[0]);                               \
            acc1[1] = fmaf(wk1, gv.y, acc1[1]);                               \
            acc1[2] = fmaf(wk1, gv.z, acc1[2]);                               \
            acc1[3] = fmaf(wk1, gv.w, acc1[3]);                               \
        }
        KSTEP(0, 0x00)
        KSTEP(1, 0x55)
        KSTEP(2, 0xAA)
        KSTEP(3, 0xFF)
#undef KSTEP
    }

    // ---- Epilogue ----
#pragma unroll
    for (int m = 0; m < 4; m++) {
        acc0[m] += __shfl_xor(acc0[m], 32, 64);   // reduce jsB bit inside wave
        acc1[m] += __shfl_xor(acc1[m], 32, 64);
    }
    zt0 += __shfl_xor(zt0, 1, 64); zt0 += __shfl_xor(zt0, 2, 64); zt0 += __shfl_xor(zt0, 32, 64);
    zt1 += __shfl_xor(zt1, 1, 64); zt1 += __shfl_xor(zt1, 2, 64); zt1 += __shfl_xor(zt1, 32, 64);
    if (lane < 32) {
        *(float4*)&redO[wv][0][hB][qB][0] = make_float4(acc0[0], acc0[1], acc0[2], acc0[3]);
        *(float4*)&redO[wv][1][hB][qB][0] = make_float4(acc1[0], acc1[1], acc1[2], acc1[3]);
        if ((lane & 3) == 0) { ztA[wv][0][hB] = zt0; ztA[wv][1][hB] = zt1; }
    }
    __syncthreads();                      // barrier 4
    if (tid < 256) {
        const int rr = tid >> 7;
        const int hf = tid & 127;
        const int oh = hf >> 4;
        const int qq = (hf >> 2) & 3;
        const int mm = hf & 3;
        float v = 0.f, z = 0.f;
#pragma unroll
        for (int w2 = 0; w2 < 8; w2++) {
            v += redO[w2][rr][oh][qq][mm];
            z += ztA[w2][rr][oh];
        }
        out[(size_t)(i0 + rr) * DIM + hf] = v / z;
    }
}

extern "C" void kernel_launch(void* const* d_in, const int* in_sizes, int n_in,
                              void* d_out, int out_size, void* d_ws, size_t ws_size,
                              hipStream_t stream) {
    const float* h      = (const float*)d_in[0];
    const int*   adj    = (const int*)  d_in[1];
    const float* s      = (const float*)d_in[2];
    const float* W      = (const float*)d_in[3];
    const float* attn_w = (const float*)d_in[4];
    float* out = (float*)d_out;

    float* g    = (float*)d_ws;                      // 1024*128
    float* srcv = g    + (size_t)NNODES * DIM;       // 1024*8
    float* dstv = srcv + (size_t)NNODES * NHEADS;    // 1024*8

    proj_kernel <<<512, 256, 0, stream>>>(h, W, attn_w, g, srcv, dstv);
    fused_kernel<<<NNODES / 2, 512, 0, stream>>>(adj, s, g, srcv, dstv, out);
}